// Round 2
// baseline (7425.558 us; speedup 1.0000x reference)
//
#include <hip/hip_runtime.h>

#define NB 16
#define NL 100
#define NOUT (16*101*101)
#define AGENT __HIP_MEMORY_SCOPE_AGENT

__device__ __forceinline__ float sigm(float x) {
    x = fminf(fmaxf(x, -30.f), 30.f);
    return 1.f / (1.f + __expf(-x));
}
__device__ __forceinline__ float tanh_(float x) {
    x = fminf(fmaxf(x, -15.f), 15.f);
    float t = __expf(2.f * x);
    return (t - 1.f) / (t + 1.f);
}

// ---------------- pack kernels ----------------

// wi0p: [dir][g][160] zero-padded from K=150
__global__ __launch_bounds__(256) void pack_wi0(const float* __restrict__ w_ih0,
                                                float* __restrict__ wi0p) {
    int idx = blockIdx.x * 256 + threadIdx.x;          // over 2*1024*160
    if (idx >= 2 * 1024 * 160) return;
    int k = idx % 160;
    int g = (idx / 160) & 1023;
    int d = idx / (160 * 1024);
    float v = (k < 150) ? w_ih0[((size_t)d * 1024 + g) * 150 + k] : 0.f;
    wi0p[idx] = v;
}

// biasp: [layer][dir][1024] = b_ih + b_hh
__global__ __launch_bounds__(256) void pack_bias(const float* __restrict__ b_ih0,
                                                 const float* __restrict__ b_hh0,
                                                 const float* __restrict__ b_ih,
                                                 const float* __restrict__ b_hh,
                                                 float* __restrict__ biasp) {
    int idx = blockIdx.x * 256 + threadIdx.x;          // over 8*1024
    if (idx >= 8 * 1024) return;
    int g = idx & 1023;
    int ld = idx >> 10;
    int l = ld >> 1, d = ld & 1;
    float v;
    if (l == 0) v = b_ih0[d * 1024 + g] + b_hh0[d * 1024 + g];
    else {
        size_t o = ((size_t)(l - 1) * 2 + d) * 1024 + g;
        v = b_ih[o] + b_hh[o];
    }
    biasp[idx] = v;
}

// x0p: [B*L][160] = [word_embeds(100) | pos_emb[pos_idx](50) | 0(10)]
__global__ __launch_bounds__(256) void concat_x0(const float* __restrict__ we,
                                                 const int* __restrict__ pos_idx,
                                                 const float* __restrict__ pos_emb,
                                                 float* __restrict__ x0p) {
    int idx = blockIdx.x * 256 + threadIdx.x;          // over 1600*160
    if (idx >= 1600 * 160) return;
    int m = idx / 160, k = idx % 160;
    float v;
    if (k < 100) v = we[(size_t)m * 100 + k];
    else if (k < 150) v = pos_emb[(size_t)pos_idx[m] * 50 + (k - 100)];
    else v = 0.f;
    x0p[idx] = v;
}

__global__ __launch_bounds__(256) void zero_out(float* __restrict__ out) {
    int idx = blockIdx.x * 256 + threadIdx.x;
    if (idx < NOUT) out[idx] = 0.f;
}

// ---------------- generic fp32 GEMM: C[m, coff+n] = bias[n] + sum_k X[m,k]*W[n,k] ----
__global__ __launch_bounds__(256) void gemm_xwT(const float* __restrict__ X,
                                                const float* __restrict__ W,
                                                const float* __restrict__ bias,
                                                float* __restrict__ C,
                                                int K, int ldx, int ldw, int ldc, int coff) {
    __shared__ float As[16][68];
    __shared__ float Bs[16][68];
    const int t = threadIdx.x;
    const int m0 = blockIdx.x * 64, n0 = blockIdx.y * 64;
    const int lr = t >> 2, lc = (t & 3) * 4;
    const int tm = (t & 15) * 4, tn = (t >> 4) * 4;
    float acc[4][4] = {};
    for (int kc = 0; kc < K; kc += 16) {
        float4 av = *(const float4*)&X[(size_t)(m0 + lr) * ldx + kc + lc];
        float4 bv = *(const float4*)&W[(size_t)(n0 + lr) * ldw + kc + lc];
        __syncthreads();
        As[lc + 0][lr] = av.x; As[lc + 1][lr] = av.y; As[lc + 2][lr] = av.z; As[lc + 3][lr] = av.w;
        Bs[lc + 0][lr] = bv.x; Bs[lc + 1][lr] = bv.y; Bs[lc + 2][lr] = bv.z; Bs[lc + 3][lr] = bv.w;
        __syncthreads();
#pragma unroll
        for (int k = 0; k < 16; ++k) {
            float4 a = *(const float4*)&As[k][tm];
            float4 b = *(const float4*)&Bs[k][tn];
            acc[0][0] = fmaf(a.x, b.x, acc[0][0]);
            acc[0][1] = fmaf(a.x, b.y, acc[0][1]);
            acc[0][2] = fmaf(a.x, b.z, acc[0][2]);
            acc[0][3] = fmaf(a.x, b.w, acc[0][3]);
            acc[1][0] = fmaf(a.y, b.x, acc[1][0]);
            acc[1][1] = fmaf(a.y, b.y, acc[1][1]);
            acc[1][2] = fmaf(a.y, b.z, acc[1][2]);
            acc[1][3] = fmaf(a.y, b.w, acc[1][3]);
            acc[2][0] = fmaf(a.z, b.x, acc[2][0]);
            acc[2][1] = fmaf(a.z, b.y, acc[2][1]);
            acc[2][2] = fmaf(a.z, b.z, acc[2][2]);
            acc[2][3] = fmaf(a.z, b.w, acc[2][3]);
            acc[3][0] = fmaf(a.w, b.x, acc[3][0]);
            acc[3][1] = fmaf(a.w, b.y, acc[3][1]);
            acc[3][2] = fmaf(a.w, b.z, acc[3][2]);
            acc[3][3] = fmaf(a.w, b.w, acc[3][3]);
        }
    }
#pragma unroll
    for (int r = 0; r < 4; ++r) {
#pragma unroll
        for (int c = 0; c < 4; ++c) {
            float v = acc[r][c];
            if (bias) v += bias[n0 + tn + c];
            C[(size_t)(m0 + tm + r) * ldc + coff + n0 + tn + c] = v;
        }
    }
}

// ---------------- weight-stationary persistent LSTM layer ----------------
// grid: 32 blocks = 2 dirs x 16 unit-slices; block 512 threads.
// Each block owns units [sid*16, sid*16+16) of its dir: 64 rows of w_hh in
// registers (128 floats/thread). Per step: gates = W x h (h in LDS), butterfly
// reduce over k-splits, activation, h exchanged via double-buffered global
// array with agent-scope release/acquire + per-(dir,step) arrival counters.
// gx: [2][B*L][1024] (x@w_ih^T + biases), whh: [2][1024][256] this layer
// hbuf: [2 parity][2 dir][256][16], cnt: [2 dir][100] (zeroed per launch)
__global__ __launch_bounds__(512) void lstm_ws(const float* __restrict__ gx,
                                               const float* __restrict__ whh,
                                               float* __restrict__ xout,
                                               float* __restrict__ hbuf,
                                               int* __restrict__ cnt) {
    const int d   = blockIdx.x >> 4;
    const int sid = blockIdx.x & 15;
    const int u0  = sid * 16;
    const int t   = threadIdx.x;
    const int b4  = t & 3;          // batch quad
    const int kk  = (t >> 2) & 7;   // k-split (32 k each)
    const int rr  = t >> 5;         // row quad (rows rr*4 .. rr*4+3)

    __shared__ __align__(16) float hs[4096];      // swizzled [kk][kx^][16b]
    __shared__ float gbuf[64 * 17];
    __shared__ float cls[16 * 17];

    // ---- load weights into registers: w[j][kx] = w_hh[row(rr,j)][kk*32+kx]
    float w[4][32];
#pragma unroll
    for (int j = 0; j < 4; ++j) {
        int lr = rr * 4 + j;
        int row = (lr >> 4) * 256 + u0 + (lr & 15);
        const float4* src = (const float4*)&whh[((size_t)d * 1024 + row) * 256 + kk * 32];
#pragma unroll
        for (int x = 0; x < 8; ++x) {
            float4 v = src[x];
            w[j][x * 4 + 0] = v.x; w[j][x * 4 + 1] = v.y;
            w[j][x * 4 + 2] = v.z; w[j][x * 4 + 3] = v.w;
        }
    }
    for (int i = t; i < 4096; i += 512) hs[i] = 0.f;
    for (int i = t; i < 16 * 17; i += 512) cls[i] = 0.f;
    __syncthreads();

    const int px = (kk & 1) * 16;                 // bank swizzle
    const float* hbE = hs + kk * 512 + b4 * 4 + px;        // even kx
    const float* hbO = hs + kk * 512 + b4 * 4 - px + 16;   // odd kx: (kx*16)^px with bit4 set

    for (int s = 0; s < NL; ++s) {
        const int tt = d ? (NL - 1 - s) : s;

        // prefetch gx for this block's rows (only kk==0 lanes use it)
        float4 g4v[4];
        const int lr0 = rr * 4;
        const int row0 = (lr0 >> 4) * 256 + u0 + (lr0 & 15);
        if (kk == 0) {
#pragma unroll
            for (int bi = 0; bi < 4; ++bi) {
                int b = b4 * 4 + bi;
                g4v[bi] = *(const float4*)&gx[((size_t)d * 1600 + b * 100 + tt) * 1024 + row0];
            }
        }

        // ---- matvec: acc[j][bi] = sum_{kx} w[j][kx] * h[kk*32+kx][b4*4+bi]
        float acc[4][4] = {};
#pragma unroll
        for (int k2 = 0; k2 < 16; ++k2) {
            float4 hA = *(const float4*)&hbE[(2 * k2) * 16];
            float4 hB = *(const float4*)&hbO[(2 * k2) * 16];   // covers kx=2*k2+1 (its *16 bit4 folded into base)
#pragma unroll
            for (int j = 0; j < 4; ++j) {
                float wa = w[j][2 * k2], wb = w[j][2 * k2 + 1];
                acc[j][0] = fmaf(wa, hA.x, acc[j][0]);
                acc[j][1] = fmaf(wa, hA.y, acc[j][1]);
                acc[j][2] = fmaf(wa, hA.z, acc[j][2]);
                acc[j][3] = fmaf(wa, hA.w, acc[j][3]);
                acc[j][0] = fmaf(wb, hB.x, acc[j][0]);
                acc[j][1] = fmaf(wb, hB.y, acc[j][1]);
                acc[j][2] = fmaf(wb, hB.z, acc[j][2]);
                acc[j][3] = fmaf(wb, hB.w, acc[j][3]);
            }
        }

        // ---- butterfly reduce over kk (lane bits 2..4)
#pragma unroll
        for (int j = 0; j < 4; ++j)
#pragma unroll
            for (int bi = 0; bi < 4; ++bi) {
                float v = acc[j][bi];
                v += __shfl_xor(v, 4);
                v += __shfl_xor(v, 8);
                v += __shfl_xor(v, 16);
                acc[j][bi] = v;
            }

        if (kk == 0) {
#pragma unroll
            for (int bi = 0; bi < 4; ++bi) {
                int b = b4 * 4 + bi;
                gbuf[(lr0 + 0) * 17 + b] = acc[0][bi] + g4v[bi].x;
                gbuf[(lr0 + 1) * 17 + b] = acc[1][bi] + g4v[bi].y;
                gbuf[(lr0 + 2) * 17 + b] = acc[2][bi] + g4v[bi].z;
                gbuf[(lr0 + 3) * 17 + b] = acc[3][bi] + g4v[bi].w;
            }
        }
        __syncthreads();

        // ---- activation (256 threads: b = t>>4, m = t&15)
        if (t < 256) {
            int b = t >> 4, m = t & 15;
            float gi = gbuf[(m) * 17 + b];
            float gf = gbuf[(16 + m) * 17 + b];
            float gg = gbuf[(32 + m) * 17 + b];
            float go = gbuf[(48 + m) * 17 + b];
            float c  = cls[m * 17 + b];
            float cn = fmaf(sigm(gf), c, sigm(gi) * tanh_(gg));
            cls[m * 17 + b] = cn;
            float hn = sigm(go) * tanh_(cn);
            hbuf[(((size_t)(s & 1) * 2 + d) * 256 + u0 + m) * 16 + b] = hn;
            xout[((size_t)b * NL + tt) * 512 + d * 256 + u0 + m] = hn;
        }
        __threadfence();          // release h slice to agent scope
        __syncthreads();

        if (s < NL - 1) {
            if (t == 0)
                __hip_atomic_fetch_add(&cnt[d * NL + s], 1, __ATOMIC_RELEASE, AGENT);
            if (t == 0) {
                int it = 0;
                while (__hip_atomic_load(&cnt[d * NL + s], __ATOMIC_ACQUIRE, AGENT) < 16
                       && it < (1 << 28)) ++it;
            }
            __syncthreads();
            __threadfence();      // acquire: invalidate stale cache lines
            // ---- stage h(step s) -> LDS (swizzled)
            const float* hg = hbuf + ((size_t)(s & 1) * 2 + d) * 4096;
            int f0 = t * 8;
            int k = f0 >> 4, bo = f0 & 15;
            float4 v0 = *(const float4*)&hg[f0];
            float4 v1 = *(const float4*)&hg[f0 + 4];
            int kkw = k >> 5, kxw = k & 31;
            float* dst = &hs[kkw * 512 + ((kxw ^ (kkw & 1)) * 16) + bo];
            *(float4*)dst = v0;
            *(float4*)(dst + 4) = v1;
            __syncthreads();
        }
    }
}

// ---------------- fused scorer ----------------
__global__ __launch_bounds__(256) void scorer_kernel(const float* __restrict__ hfr,
                                                     const float* __restrict__ W2,
                                                     const float* __restrict__ b1,
                                                     const float* __restrict__ b2,
                                                     const float* __restrict__ W3,
                                                     const float* __restrict__ b3,
                                                     const int* __restrict__ sen_lens,
                                                     float* __restrict__ out) {
    const int t = threadIdx.x;
    const int b = blockIdx.z;
    const int i0 = blockIdx.x * 8;
    const int j0 = blockIdx.y * 16;

    __shared__ float h1s[32][130];
    __shared__ float w2s[32][130];
    __shared__ float hfs[8][33];
    __shared__ float hrs[16][33];
    __shared__ float b1s[32];
    __shared__ float part[128][17];

    const int pg = t & 15;
    const int ng = t >> 4;
    const int wn = t >> 1;
    const int wk = (t & 1) * 16;
    float acc[8][8] = {};

    for (int kc = 0; kc < 512; kc += 32) {
        float4 wv0 = *(const float4*)&W2[(size_t)wn * 512 + kc + wk + 0];
        float4 wv1 = *(const float4*)&W2[(size_t)wn * 512 + kc + wk + 4];
        float4 wv2 = *(const float4*)&W2[(size_t)wn * 512 + kc + wk + 8];
        float4 wv3 = *(const float4*)&W2[(size_t)wn * 512 + kc + wk + 12];
        float4 sv = make_float4(0.f, 0.f, 0.f, 0.f);
        if (t < 64) {
            int row = t >> 3, c = (t & 7) * 4;
            int i = i0 + row;
            if (i < 100) sv = *(const float4*)&hfr[((size_t)b * 100 + i) * 1024 + kc + c];
        } else if (t < 192) {
            int idx = t - 64, row = idx >> 3, c = (idx & 7) * 4;
            int j = j0 + row;
            if (j >= 1 && j <= 100)
                sv = *(const float4*)&hfr[((size_t)b * 100 + j - 1) * 1024 + 512 + kc + c];
        } else if (t < 200) {
            sv = *(const float4*)&b1[kc + (t - 192) * 4];
        }
        __syncthreads();
        if (t < 64) {
            int row = t >> 3, c = (t & 7) * 4;
            hfs[row][c + 0] = sv.x; hfs[row][c + 1] = sv.y; hfs[row][c + 2] = sv.z; hfs[row][c + 3] = sv.w;
        } else if (t < 192) {
            int idx = t - 64, row = idx >> 3, c = (idx & 7) * 4;
            hrs[row][c + 0] = sv.x; hrs[row][c + 1] = sv.y; hrs[row][c + 2] = sv.z; hrs[row][c + 3] = sv.w;
        } else if (t < 200) {
            int c = (t - 192) * 4;
            b1s[c + 0] = sv.x; b1s[c + 1] = sv.y; b1s[c + 2] = sv.z; b1s[c + 3] = sv.w;
        }
        w2s[wk + 0][wn] = wv0.x;  w2s[wk + 1][wn] = wv0.y;  w2s[wk + 2][wn] = wv0.z;  w2s[wk + 3][wn] = wv0.w;
        w2s[wk + 4][wn] = wv1.x;  w2s[wk + 5][wn] = wv1.y;  w2s[wk + 6][wn] = wv1.z;  w2s[wk + 7][wn] = wv1.w;
        w2s[wk + 8][wn] = wv2.x;  w2s[wk + 9][wn] = wv2.y;  w2s[wk + 10][wn] = wv2.z; w2s[wk + 11][wn] = wv2.w;
        w2s[wk + 12][wn] = wv3.x; w2s[wk + 13][wn] = wv3.y; w2s[wk + 14][wn] = wv3.z; w2s[wk + 15][wn] = wv3.w;
        __syncthreads();
        {
            int p = t & 127, kh = (t >> 7) * 16;
            int pi = p >> 4, pj = p & 15;
#pragma unroll
            for (int kkx = 0; kkx < 16; ++kkx) {
                int k = kh + kkx;
                h1s[k][p] = fmaxf(hfs[pi][k] + hrs[pj][k] + b1s[k], 0.f);
            }
        }
        __syncthreads();
#pragma unroll 4
        for (int k = 0; k < 32; ++k) {
            float4 a0 = *(const float4*)&h1s[k][pg * 8];
            float4 a1 = *(const float4*)&h1s[k][pg * 8 + 4];
            float4 c0 = *(const float4*)&w2s[k][ng * 8];
            float4 c1 = *(const float4*)&w2s[k][ng * 8 + 4];
            float av[8] = {a0.x, a0.y, a0.z, a0.w, a1.x, a1.y, a1.z, a1.w};
            float cv[8] = {c0.x, c0.y, c0.z, c0.w, c1.x, c1.y, c1.z, c1.w};
#pragma unroll
            for (int r = 0; r < 8; ++r)
#pragma unroll
                for (int c = 0; c < 8; ++c)
                    acc[r][c] = fmaf(av[r], cv[c], acc[r][c]);
        }
    }
    float w3r[8], b2r[8];
#pragma unroll
    for (int c = 0; c < 8; ++c) {
        w3r[c] = W3[ng * 8 + c];
        b2r[c] = b2[ng * 8 + c];
    }
#pragma unroll
    for (int r = 0; r < 8; ++r) {
        float sp = 0.f;
#pragma unroll
        for (int c = 0; c < 8; ++c)
            sp += fmaxf(acc[r][c] + b2r[c], 0.f) * w3r[c];
        part[pg * 8 + r][ng] = sp;
    }
    __syncthreads();
    if (t < 128) {
        float s = 0.f;
#pragma unroll
        for (int g2 = 0; g2 < 16; ++g2) s += part[t][g2];
        int i = i0 + (t >> 4), j = j0 + (t & 15);
        if (i < 100 && j < 101) {
            float v = s + b3[0];
            int sl = sen_lens[b];
            if (!((i < sl) && (j <= sl)) || (i == 0 && j == 0)) v = 0.f;
            out[((size_t)b * 101 + i) * 101 + j] = v;
        }
    }
}

// ---------------- launcher ----------------
extern "C" void kernel_launch(void* const* d_in, const int* in_sizes, int n_in,
                              void* d_out, int out_size, void* d_ws, size_t ws_size,
                              hipStream_t stream) {
    const float* we       = (const float*)d_in[0];
    const int*   pos_idx  = (const int*)d_in[1];
    const int*   sen_lens = (const int*)d_in[2];
    const float* pos_emb  = (const float*)d_in[3];
    const float* w_ih0    = (const float*)d_in[4];
    const float* w_hh0    = (const float*)d_in[5];
    const float* b_ih0    = (const float*)d_in[6];
    const float* b_hh0    = (const float*)d_in[7];
    const float* w_ih     = (const float*)d_in[8];
    const float* w_hh     = (const float*)d_in[9];
    const float* b_ih     = (const float*)d_in[10];
    const float* b_hh     = (const float*)d_in[11];
    const float* W1       = (const float*)d_in[12];
    const float* b1       = (const float*)d_in[13];
    const float* W2       = (const float*)d_in[14];
    const float* b2       = (const float*)d_in[15];
    const float* W3       = (const float*)d_in[16];
    const float* b3       = (const float*)d_in[17];
    float* out = (float*)d_out;

    float* ws    = (float*)d_ws;
    float* x0p   = ws;                      // 256000
    float* gx    = x0p + 256000;            // 3276800
    float* xA    = gx + 3276800;            // 819200
    float* xB    = xA + 819200;             // 819200
    float* hfr   = xB + 819200;             // 1638400
    float* wi0p  = hfr + 1638400;           // 327680
    float* biasp = wi0p + 327680;           // 8192
    float* hbuf  = biasp + 8192;            // 16384 (2 parity x 2 dir x 256 x 16)
    int*   cnt   = (int*)(hbuf + 16384);    // 800 ints [4 layers][2 dirs][100]

    hipMemsetAsync(cnt, 0, 800 * sizeof(int), stream);
    pack_wi0<<<1280, 256, 0, stream>>>(w_ih0, wi0p);
    pack_bias<<<32, 256, 0, stream>>>(b_ih0, b_hh0, b_ih, b_hh, biasp);
    concat_x0<<<1000, 256, 0, stream>>>(we, pos_idx, pos_emb, x0p);

    // layer 0: K=160 (padded)
    for (int d = 0; d < 2; ++d)
        gemm_xwT<<<dim3(25, 16), 256, 0, stream>>>(
            x0p, wi0p + (size_t)d * 1024 * 160, biasp + d * 1024,
            gx + (size_t)d * 1600 * 1024, 160, 160, 160, 1024, 0);
    lstm_ws<<<32, 512, 0, stream>>>(gx, w_hh0, xA, hbuf, cnt);

    const float* xin = xA;
    float* xo = xB;
    for (int l = 1; l < 4; ++l) {
        for (int d = 0; d < 2; ++d)
            gemm_xwT<<<dim3(25, 16), 256, 0, stream>>>(
                xin, w_ih + (((size_t)(l - 1) * 2 + d) * 1024) * 512,
                biasp + (l * 2 + d) * 1024,
                gx + (size_t)d * 1600 * 1024, 512, 512, 512, 1024, 0);
        lstm_ws<<<32, 512, 0, stream>>>(gx, w_hh + (size_t)(l - 1) * 524288,
                                        xo, hbuf, cnt + l * 200);
        float* tmp = (float*)xin; xin = xo; xo = tmp;
    }
    const float* lstm_out = xin;

    gemm_xwT<<<dim3(25, 8), 256, 0, stream>>>(lstm_out, W1, nullptr, hfr,
                                              512, 512, 1024, 1024, 0);
    gemm_xwT<<<dim3(25, 8), 256, 0, stream>>>(lstm_out, W1 + 512, nullptr, hfr,
                                              512, 512, 1024, 1024, 512);

    zero_out<<<(NOUT + 255) / 256, 256, 0, stream>>>(out);
    scorer_kernel<<<dim3(13, 7, 16), 256, 0, stream>>>(hfr, W2, b1, b2, W3, b3,
                                                       sen_lens, out);
}

// Round 3
// 2104.048 us; speedup vs baseline: 3.5292x; 3.5292x over previous
//
#include <hip/hip_runtime.h>
#include <stdint.h>

#define NB 16
#define NL 100
#define NOUT (16*101*101)

typedef _Float16 half2v __attribute__((ext_vector_type(2)));

__device__ __forceinline__ float sigm(float x) {
    x = fminf(fmaxf(x, -30.f), 30.f);
    return 1.f / (1.f + __expf(-x));
}
__device__ __forceinline__ float tanh_(float x) {
    x = fminf(fmaxf(x, -15.f), 15.f);
    float t = __expf(2.f * x);
    return (t - 1.f) / (t + 1.f);
}

__device__ __forceinline__ float dot2f(uint32_t w, uint32_t h, float acc) {
#if defined(__has_builtin) && __has_builtin(__builtin_amdgcn_fdot2)
    return __builtin_amdgcn_fdot2(__builtin_bit_cast(half2v, w),
                                  __builtin_bit_cast(half2v, h), acc, false);
#else
    half2v a = __builtin_bit_cast(half2v, w), b = __builtin_bit_cast(half2v, h);
    return acc + (float)a.x * (float)b.x + (float)a.y * (float)b.y;
#endif
}

// ---------------- pack kernels ----------------

// whh16: [4 layer][2 dir][1024 row][256 k] fp16
__global__ __launch_bounds__(256) void pack_whh16(const float* __restrict__ w_hh0,
                                                  const float* __restrict__ w_hh,
                                                  _Float16* __restrict__ whh16) {
    int idx = blockIdx.x * 256 + threadIdx.x;          // over 4*524288
    if (idx >= 4 * 524288) return;
    int l = idx >> 19;
    int r = idx & 524287;
    float v = (l == 0) ? w_hh0[r] : w_hh[(size_t)(l - 1) * 524288 + r];
    whh16[idx] = (_Float16)v;
}

// wi0p: [dir][g][160] zero-padded from K=150
__global__ __launch_bounds__(256) void pack_wi0(const float* __restrict__ w_ih0,
                                                float* __restrict__ wi0p) {
    int idx = blockIdx.x * 256 + threadIdx.x;          // over 2*1024*160
    if (idx >= 2 * 1024 * 160) return;
    int k = idx % 160;
    int g = (idx / 160) & 1023;
    int d = idx / (160 * 1024);
    float v = (k < 150) ? w_ih0[((size_t)d * 1024 + g) * 150 + k] : 0.f;
    wi0p[idx] = v;
}

// biasp: [layer][dir][1024] = b_ih + b_hh
__global__ __launch_bounds__(256) void pack_bias(const float* __restrict__ b_ih0,
                                                 const float* __restrict__ b_hh0,
                                                 const float* __restrict__ b_ih,
                                                 const float* __restrict__ b_hh,
                                                 float* __restrict__ biasp) {
    int idx = blockIdx.x * 256 + threadIdx.x;          // over 8*1024
    if (idx >= 8 * 1024) return;
    int g = idx & 1023;
    int ld = idx >> 10;
    int l = ld >> 1, d = ld & 1;
    float v;
    if (l == 0) v = b_ih0[d * 1024 + g] + b_hh0[d * 1024 + g];
    else {
        size_t o = ((size_t)(l - 1) * 2 + d) * 1024 + g;
        v = b_ih[o] + b_hh[o];
    }
    biasp[idx] = v;
}

// x0p: [B*L][160] = [word_embeds(100) | pos_emb[pos_idx](50) | 0(10)]
__global__ __launch_bounds__(256) void concat_x0(const float* __restrict__ we,
                                                 const int* __restrict__ pos_idx,
                                                 const float* __restrict__ pos_emb,
                                                 float* __restrict__ x0p) {
    int idx = blockIdx.x * 256 + threadIdx.x;          // over 1600*160
    if (idx >= 1600 * 160) return;
    int m = idx / 160, k = idx % 160;
    float v;
    if (k < 100) v = we[(size_t)m * 100 + k];
    else if (k < 150) v = pos_emb[(size_t)pos_idx[m] * 50 + (k - 100)];
    else v = 0.f;
    x0p[idx] = v;
}

__global__ __launch_bounds__(256) void zero_out(float* __restrict__ out) {
    int idx = blockIdx.x * 256 + threadIdx.x;
    if (idx < NOUT) out[idx] = 0.f;
}

// ---------------- generic fp32 GEMM: C[m, coff+n] = bias[n] + sum_k X[m,k]*W[n,k] ----
__global__ __launch_bounds__(256) void gemm_xwT(const float* __restrict__ X,
                                                const float* __restrict__ W,
                                                const float* __restrict__ bias,
                                                float* __restrict__ C,
                                                int K, int ldx, int ldw, int ldc, int coff) {
    __shared__ float As[16][68];
    __shared__ float Bs[16][68];
    const int t = threadIdx.x;
    const int m0 = blockIdx.x * 64, n0 = blockIdx.y * 64;
    const int lr = t >> 2, lc = (t & 3) * 4;
    const int tm = (t & 15) * 4, tn = (t >> 4) * 4;
    float acc[4][4] = {};
    for (int kc = 0; kc < K; kc += 16) {
        float4 av = *(const float4*)&X[(size_t)(m0 + lr) * ldx + kc + lc];
        float4 bv = *(const float4*)&W[(size_t)(n0 + lr) * ldw + kc + lc];
        __syncthreads();
        As[lc + 0][lr] = av.x; As[lc + 1][lr] = av.y; As[lc + 2][lr] = av.z; As[lc + 3][lr] = av.w;
        Bs[lc + 0][lr] = bv.x; Bs[lc + 1][lr] = bv.y; Bs[lc + 2][lr] = bv.z; Bs[lc + 3][lr] = bv.w;
        __syncthreads();
#pragma unroll
        for (int k = 0; k < 16; ++k) {
            float4 a = *(const float4*)&As[k][tm];
            float4 b = *(const float4*)&Bs[k][tn];
            acc[0][0] = fmaf(a.x, b.x, acc[0][0]);
            acc[0][1] = fmaf(a.x, b.y, acc[0][1]);
            acc[0][2] = fmaf(a.x, b.z, acc[0][2]);
            acc[0][3] = fmaf(a.x, b.w, acc[0][3]);
            acc[1][0] = fmaf(a.y, b.x, acc[1][0]);
            acc[1][1] = fmaf(a.y, b.y, acc[1][1]);
            acc[1][2] = fmaf(a.y, b.z, acc[1][2]);
            acc[1][3] = fmaf(a.y, b.w, acc[1][3]);
            acc[2][0] = fmaf(a.z, b.x, acc[2][0]);
            acc[2][1] = fmaf(a.z, b.y, acc[2][1]);
            acc[2][2] = fmaf(a.z, b.z, acc[2][2]);
            acc[2][3] = fmaf(a.z, b.w, acc[2][3]);
            acc[3][0] = fmaf(a.w, b.x, acc[3][0]);
            acc[3][1] = fmaf(a.w, b.y, acc[3][1]);
            acc[3][2] = fmaf(a.w, b.z, acc[3][2]);
            acc[3][3] = fmaf(a.w, b.w, acc[3][3]);
        }
    }
#pragma unroll
    for (int r = 0; r < 4; ++r) {
#pragma unroll
        for (int c = 0; c < 4; ++c) {
            float v = acc[r][c];
            if (bias) v += bias[n0 + tn + c];
            C[(size_t)(m0 + tm + r) * ldc + coff + n0 + tn + c] = v;
        }
    }
}

// ---------------- register/LDS-resident fp16 LSTM recurrence ----------------
// 32 blocks = 2 dir x 16 batch; 1024 threads; thread t owns gate-row t.
// Weights (fp16): k-pairs [0,96) in VGPRs (96 dwords/thread), pairs [96,128)
// in LDS (128 KB, layout [c2][row][2] for 2-way-free ds_read_b64).
// h (fp16 pairs) + gates (f32) exchanged through LDS; c-state in registers
// of threads t<256. No global traffic per step except gx read + h write.
__global__ __launch_bounds__(1024, 4) void lstm_reg(const float* __restrict__ gx,
                                                    const _Float16* __restrict__ whh16,
                                                    float* __restrict__ xout) {
    extern __shared__ uint32_t smem[];
    uint32_t* wlds = smem;                   // 32768 dwords = 128 KB
    uint32_t* hs   = smem + 32768;           // 128 dwords (256 fp16)
    float*    gbuf = (float*)(smem + 32896); // 1024 floats

    const int d = blockIdx.x >> 4;
    const int b = blockIdx.x & 15;
    const int t = threadIdx.x;

    // ---- one-time: load weights
    const _Float16* wrow = whh16 + ((size_t)d * 1024 + t) * 256;
    uint32_t wreg[96];
    {
        const uint4* wr4 = (const uint4*)wrow;       // 16 B = 4 pairs
#pragma unroll
        for (int i = 0; i < 24; ++i) {
            uint4 v = wr4[i];
            wreg[i * 4 + 0] = v.x; wreg[i * 4 + 1] = v.y;
            wreg[i * 4 + 2] = v.z; wreg[i * 4 + 3] = v.w;
        }
        const uint2* wtail = (const uint2*)(wrow + 192);  // 16 uint2 = pairs 96..127
#pragma unroll
        for (int c2 = 0; c2 < 16; ++c2) {
            uint2 v = wtail[c2];
            *(uint2*)(wlds + c2 * 2048 + (t << 1)) = v;
        }
    }
    if (t < 128) hs[t] = 0u;
    float creg = 0.f;
    __syncthreads();

    const float* gxb = gx + ((size_t)d * 1600 + b * 100) * 1024;

    for (int s = 0; s < NL; ++s) {
        const int tt = d ? (NL - 1 - s) : s;
        float gxv = gxb[(size_t)tt * 1024 + t];

        float acc = 0.f;
        const uint4* hp4 = (const uint4*)hs;
#pragma unroll
        for (int c4 = 0; c4 < 24; ++c4) {
            uint4 h4 = hp4[c4];
            acc = dot2f(wreg[c4 * 4 + 0], h4.x, acc);
            acc = dot2f(wreg[c4 * 4 + 1], h4.y, acc);
            acc = dot2f(wreg[c4 * 4 + 2], h4.z, acc);
            acc = dot2f(wreg[c4 * 4 + 3], h4.w, acc);
        }
        const uint2* hp2 = (const uint2*)hs;
#pragma unroll
        for (int c2 = 0; c2 < 16; ++c2) {
            uint2 wp = *(const uint2*)(wlds + c2 * 2048 + (t << 1));
            uint2 h2 = hp2[48 + c2];
            acc = dot2f(wp.x, h2.x, acc);
            acc = dot2f(wp.y, h2.y, acc);
        }
        gbuf[t] = acc + gxv;
        __syncthreads();

        if (t < 256) {
            float gi = gbuf[t];
            float gf = gbuf[256 + t];
            float gg = gbuf[512 + t];
            float go = gbuf[768 + t];
            float cn = fmaf(sigm(gf), creg, sigm(gi) * tanh_(gg));
            creg = cn;
            float hn = sigm(go) * tanh_(cn);
            ((_Float16*)hs)[t] = (_Float16)hn;
            xout[((size_t)b * NL + tt) * 512 + d * 256 + t] = hn;
        }
        __syncthreads();
    }
}

// ---------------- fused scorer ----------------
__global__ __launch_bounds__(256) void scorer_kernel(const float* __restrict__ hfr,
                                                     const float* __restrict__ W2,
                                                     const float* __restrict__ b1,
                                                     const float* __restrict__ b2,
                                                     const float* __restrict__ W3,
                                                     const float* __restrict__ b3,
                                                     const int* __restrict__ sen_lens,
                                                     float* __restrict__ out) {
    const int t = threadIdx.x;
    const int b = blockIdx.z;
    const int i0 = blockIdx.x * 8;
    const int j0 = blockIdx.y * 16;

    __shared__ float h1s[32][130];
    __shared__ float w2s[32][130];
    __shared__ float hfs[8][33];
    __shared__ float hrs[16][33];
    __shared__ float b1s[32];
    __shared__ float part[128][17];

    const int pg = t & 15;
    const int ng = t >> 4;
    const int wn = t >> 1;
    const int wk = (t & 1) * 16;
    float acc[8][8] = {};

    for (int kc = 0; kc < 512; kc += 32) {
        float4 wv0 = *(const float4*)&W2[(size_t)wn * 512 + kc + wk + 0];
        float4 wv1 = *(const float4*)&W2[(size_t)wn * 512 + kc + wk + 4];
        float4 wv2 = *(const float4*)&W2[(size_t)wn * 512 + kc + wk + 8];
        float4 wv3 = *(const float4*)&W2[(size_t)wn * 512 + kc + wk + 12];
        float4 sv = make_float4(0.f, 0.f, 0.f, 0.f);
        if (t < 64) {
            int row = t >> 3, c = (t & 7) * 4;
            int i = i0 + row;
            if (i < 100) sv = *(const float4*)&hfr[((size_t)b * 100 + i) * 1024 + kc + c];
        } else if (t < 192) {
            int idx = t - 64, row = idx >> 3, c = (idx & 7) * 4;
            int j = j0 + row;
            if (j >= 1 && j <= 100)
                sv = *(const float4*)&hfr[((size_t)b * 100 + j - 1) * 1024 + 512 + kc + c];
        } else if (t < 200) {
            sv = *(const float4*)&b1[kc + (t - 192) * 4];
        }
        __syncthreads();
        if (t < 64) {
            int row = t >> 3, c = (t & 7) * 4;
            hfs[row][c + 0] = sv.x; hfs[row][c + 1] = sv.y; hfs[row][c + 2] = sv.z; hfs[row][c + 3] = sv.w;
        } else if (t < 192) {
            int idx = t - 64, row = idx >> 3, c = (idx & 7) * 4;
            hrs[row][c + 0] = sv.x; hrs[row][c + 1] = sv.y; hrs[row][c + 2] = sv.z; hrs[row][c + 3] = sv.w;
        } else if (t < 200) {
            int c = (t - 192) * 4;
            b1s[c + 0] = sv.x; b1s[c + 1] = sv.y; b1s[c + 2] = sv.z; b1s[c + 3] = sv.w;
        }
        w2s[wk + 0][wn] = wv0.x;  w2s[wk + 1][wn] = wv0.y;  w2s[wk + 2][wn] = wv0.z;  w2s[wk + 3][wn] = wv0.w;
        w2s[wk + 4][wn] = wv1.x;  w2s[wk + 5][wn] = wv1.y;  w2s[wk + 6][wn] = wv1.z;  w2s[wk + 7][wn] = wv1.w;
        w2s[wk + 8][wn] = wv2.x;  w2s[wk + 9][wn] = wv2.y;  w2s[wk + 10][wn] = wv2.z; w2s[wk + 11][wn] = wv2.w;
        w2s[wk + 12][wn] = wv3.x; w2s[wk + 13][wn] = wv3.y; w2s[wk + 14][wn] = wv3.z; w2s[wk + 15][wn] = wv3.w;
        __syncthreads();
        {
            int p = t & 127, kh = (t >> 7) * 16;
            int pi = p >> 4, pj = p & 15;
#pragma unroll
            for (int kkx = 0; kkx < 16; ++kkx) {
                int k = kh + kkx;
                h1s[k][p] = fmaxf(hfs[pi][k] + hrs[pj][k] + b1s[k], 0.f);
            }
        }
        __syncthreads();
#pragma unroll 4
        for (int k = 0; k < 32; ++k) {
            float4 a0 = *(const float4*)&h1s[k][pg * 8];
            float4 a1 = *(const float4*)&h1s[k][pg * 8 + 4];
            float4 c0 = *(const float4*)&w2s[k][ng * 8];
            float4 c1 = *(const float4*)&w2s[k][ng * 8 + 4];
            float av[8] = {a0.x, a0.y, a0.z, a0.w, a1.x, a1.y, a1.z, a1.w};
            float cv[8] = {c0.x, c0.y, c0.z, c0.w, c1.x, c1.y, c1.z, c1.w};
#pragma unroll
            for (int r = 0; r < 8; ++r)
#pragma unroll
                for (int c = 0; c < 8; ++c)
                    acc[r][c] = fmaf(av[r], cv[c], acc[r][c]);
        }
    }
    float w3r[8], b2r[8];
#pragma unroll
    for (int c = 0; c < 8; ++c) {
        w3r[c] = W3[ng * 8 + c];
        b2r[c] = b2[ng * 8 + c];
    }
#pragma unroll
    for (int r = 0; r < 8; ++r) {
        float sp = 0.f;
#pragma unroll
        for (int c = 0; c < 8; ++c)
            sp += fmaxf(acc[r][c] + b2r[c], 0.f) * w3r[c];
        part[pg * 8 + r][ng] = sp;
    }
    __syncthreads();
    if (t < 128) {
        float s = 0.f;
#pragma unroll
        for (int g2 = 0; g2 < 16; ++g2) s += part[t][g2];
        int i = i0 + (t >> 4), j = j0 + (t & 15);
        if (i < 100 && j < 101) {
            float v = s + b3[0];
            int sl = sen_lens[b];
            if (!((i < sl) && (j <= sl)) || (i == 0 && j == 0)) v = 0.f;
            out[((size_t)b * 101 + i) * 101 + j] = v;
        }
    }
}

// ---------------- launcher ----------------
extern "C" void kernel_launch(void* const* d_in, const int* in_sizes, int n_in,
                              void* d_out, int out_size, void* d_ws, size_t ws_size,
                              hipStream_t stream) {
    const float* we       = (const float*)d_in[0];
    const int*   pos_idx  = (const int*)d_in[1];
    const int*   sen_lens = (const int*)d_in[2];
    const float* pos_emb  = (const float*)d_in[3];
    const float* w_ih0    = (const float*)d_in[4];
    const float* w_hh0    = (const float*)d_in[5];
    const float* b_ih0    = (const float*)d_in[6];
    const float* b_hh0    = (const float*)d_in[7];
    const float* w_ih     = (const float*)d_in[8];
    const float* w_hh     = (const float*)d_in[9];
    const float* b_ih     = (const float*)d_in[10];
    const float* b_hh     = (const float*)d_in[11];
    const float* W1       = (const float*)d_in[12];
    const float* b1       = (const float*)d_in[13];
    const float* W2       = (const float*)d_in[14];
    const float* b2       = (const float*)d_in[15];
    const float* W3       = (const float*)d_in[16];
    const float* b3       = (const float*)d_in[17];
    float* out = (float*)d_out;

    float* ws    = (float*)d_ws;
    float* x0p   = ws;                      // 256000
    float* gx    = x0p + 256000;            // 3276800
    float* xA    = gx + 3276800;            // 819200
    float* xB    = xA + 819200;             // 819200
    float* hfr   = xB + 819200;             // 1638400
    float* wi0p  = hfr + 1638400;           // 327680
    float* biasp = wi0p + 327680;           // 8192
    _Float16* whh16 = (_Float16*)(biasp + 8192);  // 2097152 halves = 4 MB

    pack_whh16<<<8192, 256, 0, stream>>>(w_hh0, w_hh, whh16);
    pack_wi0<<<1280, 256, 0, stream>>>(w_ih0, wi0p);
    pack_bias<<<32, 256, 0, stream>>>(b_ih0, b_hh0, b_ih, b_hh, biasp);
    concat_x0<<<1000, 256, 0, stream>>>(we, pos_idx, pos_emb, x0p);

    const int LSTM_SMEM = (32768 + 128 + 1024) * 4;   // 135680 B

    // layer 0: K=160 (padded)
    for (int d = 0; d < 2; ++d)
        gemm_xwT<<<dim3(25, 16), 256, 0, stream>>>(
            x0p, wi0p + (size_t)d * 1024 * 160, biasp + d * 1024,
            gx + (size_t)d * 1600 * 1024, 160, 160, 160, 1024, 0);
    lstm_reg<<<32, 1024, LSTM_SMEM, stream>>>(gx, whh16, xA);

    const float* xin = xA;
    float* xo = xB;
    for (int l = 1; l < 4; ++l) {
        for (int d = 0; d < 2; ++d)
            gemm_xwT<<<dim3(25, 16), 256, 0, stream>>>(
                xin, w_ih + (((size_t)(l - 1) * 2 + d) * 1024) * 512,
                biasp + (l * 2 + d) * 1024,
                gx + (size_t)d * 1600 * 1024, 512, 512, 512, 1024, 0);
        lstm_reg<<<32, 1024, LSTM_SMEM, stream>>>(gx, whh16 + (size_t)l * 524288, xo);
        float* tmp = (float*)xin; xin = xo; xo = tmp;
    }
    const float* lstm_out = xin;

    gemm_xwT<<<dim3(25, 8), 256, 0, stream>>>(lstm_out, W1, nullptr, hfr,
                                              512, 512, 1024, 1024, 0);
    gemm_xwT<<<dim3(25, 8), 256, 0, stream>>>(lstm_out, W1 + 512, nullptr, hfr,
                                              512, 512, 1024, 1024, 512);

    zero_out<<<(NOUT + 255) / 256, 256, 0, stream>>>(out);
    scorer_kernel<<<dim3(13, 7, 16), 256, 0, stream>>>(hfr, W2, b1, b2, W3, b3,
                                                       sen_lens, out);
}

// Round 4
// 1205.144 us; speedup vs baseline: 6.1616x; 1.7459x over previous
//
#include <hip/hip_runtime.h>
#include <stdint.h>

#define NB 16
#define NL 100
#define NOUT (16*101*101)

typedef _Float16 f16x8 __attribute__((ext_vector_type(8)));
typedef float f32x4 __attribute__((ext_vector_type(4)));

__device__ __forceinline__ float sigm(float x) {
    x = fminf(fmaxf(x, -30.f), 30.f);
    return 1.f / (1.f + __expf(-x));
}
__device__ __forceinline__ float tanh_(float x) {
    x = fminf(fmaxf(x, -15.f), 15.f);
    float t = __expf(2.f * x);
    return (t - 1.f) / (t + 1.f);
}
__device__ __forceinline__ uint32_t pack2h(_Float16 a, _Float16 b) {
    return (uint32_t)__builtin_bit_cast(uint16_t, a) |
           ((uint32_t)__builtin_bit_cast(uint16_t, b) << 16);
}

// ---------------- pack kernels ----------------

// wpk: [layer*2+dir][mt 64][kc 8][lane 64][4 dw]  (A-frags of w_hh, f16)
// element: row = mt*16 + (l&15); k = kc*32 + (l>>4)*8 + j
__global__ __launch_bounds__(256) void pack_whh_mfma(const float* __restrict__ w_hh0,
                                                     const float* __restrict__ w_hh,
                                                     uint32_t* __restrict__ wpk) {
    int idx = blockIdx.x * 256 + threadIdx.x;          // over 8*64*8*64 = 262144
    if (idx >= 262144) return;
    int l6 = idx & 63;
    int kc = (idx >> 6) & 7;
    int mt = (idx >> 9) & 63;
    int ld = idx >> 15;
    int layer = ld >> 1, d = ld & 1;
    int row = mt * 16 + (l6 & 15);
    int k0 = kc * 32 + (l6 >> 4) * 8;
    const float* src = (layer == 0)
        ? &w_hh0[((size_t)d * 1024 + row) * 256]
        : &w_hh[(((size_t)(layer - 1) * 2 + d) * 1024 + row) * 256];
    uint4 o;
    o.x = pack2h((_Float16)src[k0 + 0], (_Float16)src[k0 + 1]);
    o.y = pack2h((_Float16)src[k0 + 2], (_Float16)src[k0 + 3]);
    o.z = pack2h((_Float16)src[k0 + 4], (_Float16)src[k0 + 5]);
    o.w = pack2h((_Float16)src[k0 + 6], (_Float16)src[k0 + 7]);
    *(uint4*)&wpk[(size_t)idx * 4] = o;
}

// w2pk: [kc 16][split 2][nt 8][lane 64][4 dw]  (B-frags of W2, split-f16)
// element: ch = nt*16 + (l&15); k = kc*32 + (l>>4)*8 + j
__global__ __launch_bounds__(256) void pack_w2_mfma(const float* __restrict__ W2,
                                                    uint32_t* __restrict__ w2pk) {
    int idx = blockIdx.x * 256 + threadIdx.x;          // over 16*2*8*64 = 16384
    if (idx >= 16384) return;
    int l6 = idx & 63;
    int nt = (idx >> 6) & 7;
    int sp = (idx >> 9) & 1;
    int kc = idx >> 10;
    int ch = nt * 16 + (l6 & 15);
    int k0 = kc * 32 + (l6 >> 4) * 8;
    uint32_t dw[4];
#pragma unroll
    for (int dwi = 0; dwi < 4; ++dwi) {
        float x0 = W2[(size_t)ch * 512 + k0 + dwi * 2 + 0];
        float x1 = W2[(size_t)ch * 512 + k0 + dwi * 2 + 1];
        _Float16 h0 = (_Float16)x0, h1 = (_Float16)x1;
        _Float16 v0 = sp ? (_Float16)(x0 - (float)h0) : h0;
        _Float16 v1 = sp ? (_Float16)(x1 - (float)h1) : h1;
        dw[dwi] = pack2h(v0, v1);
    }
    *(uint4*)&w2pk[(size_t)idx * 4] = make_uint4(dw[0], dw[1], dw[2], dw[3]);
}

// wi0p: [dir][g][160] zero-padded from K=150
__global__ __launch_bounds__(256) void pack_wi0(const float* __restrict__ w_ih0,
                                                float* __restrict__ wi0p) {
    int idx = blockIdx.x * 256 + threadIdx.x;
    if (idx >= 2 * 1024 * 160) return;
    int k = idx % 160;
    int g = (idx / 160) & 1023;
    int d = idx / (160 * 1024);
    float v = (k < 150) ? w_ih0[((size_t)d * 1024 + g) * 150 + k] : 0.f;
    wi0p[idx] = v;
}

// biasp: [layer][dir][1024] = b_ih + b_hh
__global__ __launch_bounds__(256) void pack_bias(const float* __restrict__ b_ih0,
                                                 const float* __restrict__ b_hh0,
                                                 const float* __restrict__ b_ih,
                                                 const float* __restrict__ b_hh,
                                                 float* __restrict__ biasp) {
    int idx = blockIdx.x * 256 + threadIdx.x;
    if (idx >= 8 * 1024) return;
    int g = idx & 1023;
    int ld = idx >> 10;
    int l = ld >> 1, d = ld & 1;
    float v;
    if (l == 0) v = b_ih0[d * 1024 + g] + b_hh0[d * 1024 + g];
    else {
        size_t o = ((size_t)(l - 1) * 2 + d) * 1024 + g;
        v = b_ih[o] + b_hh[o];
    }
    biasp[idx] = v;
}

// x0p: [B*L][160]
__global__ __launch_bounds__(256) void concat_x0(const float* __restrict__ we,
                                                 const int* __restrict__ pos_idx,
                                                 const float* __restrict__ pos_emb,
                                                 float* __restrict__ x0p) {
    int idx = blockIdx.x * 256 + threadIdx.x;
    if (idx >= 1600 * 160) return;
    int m = idx / 160, k = idx % 160;
    float v;
    if (k < 100) v = we[(size_t)m * 100 + k];
    else if (k < 150) v = pos_emb[(size_t)pos_idx[m] * 50 + (k - 100)];
    else v = 0.f;
    x0p[idx] = v;
}

__global__ __launch_bounds__(256) void zero_out(float* __restrict__ out) {
    int idx = blockIdx.x * 256 + threadIdx.x;
    if (idx < NOUT) out[idx] = 0.f;
}

// ---------------- fp32 GEMM (input projections + W1) ----------------
__global__ __launch_bounds__(256) void gemm_xwT(const float* __restrict__ X,
                                                const float* __restrict__ W,
                                                const float* __restrict__ bias,
                                                float* __restrict__ C,
                                                int K, int ldx, int ldw, int ldc, int coff) {
    __shared__ float As[16][68];
    __shared__ float Bs[16][68];
    const int t = threadIdx.x;
    const int m0 = blockIdx.x * 64, n0 = blockIdx.y * 64;
    const int lr = t >> 2, lc = (t & 3) * 4;
    const int tm = (t & 15) * 4, tn = (t >> 4) * 4;
    float acc[4][4] = {};
    for (int kc = 0; kc < K; kc += 16) {
        float4 av = *(const float4*)&X[(size_t)(m0 + lr) * ldx + kc + lc];
        float4 bv = *(const float4*)&W[(size_t)(n0 + lr) * ldw + kc + lc];
        __syncthreads();
        As[lc + 0][lr] = av.x; As[lc + 1][lr] = av.y; As[lc + 2][lr] = av.z; As[lc + 3][lr] = av.w;
        Bs[lc + 0][lr] = bv.x; Bs[lc + 1][lr] = bv.y; Bs[lc + 2][lr] = bv.z; Bs[lc + 3][lr] = bv.w;
        __syncthreads();
#pragma unroll
        for (int k = 0; k < 16; ++k) {
            float4 a = *(const float4*)&As[k][tm];
            float4 b = *(const float4*)&Bs[k][tn];
            acc[0][0] = fmaf(a.x, b.x, acc[0][0]);
            acc[0][1] = fmaf(a.x, b.y, acc[0][1]);
            acc[0][2] = fmaf(a.x, b.z, acc[0][2]);
            acc[0][3] = fmaf(a.x, b.w, acc[0][3]);
            acc[1][0] = fmaf(a.y, b.x, acc[1][0]);
            acc[1][1] = fmaf(a.y, b.y, acc[1][1]);
            acc[1][2] = fmaf(a.y, b.z, acc[1][2]);
            acc[1][3] = fmaf(a.y, b.w, acc[1][3]);
            acc[2][0] = fmaf(a.z, b.x, acc[2][0]);
            acc[2][1] = fmaf(a.z, b.y, acc[2][1]);
            acc[2][2] = fmaf(a.z, b.z, acc[2][2]);
            acc[2][3] = fmaf(a.z, b.w, acc[2][3]);
            acc[3][0] = fmaf(a.w, b.x, acc[3][0]);
            acc[3][1] = fmaf(a.w, b.y, acc[3][1]);
            acc[3][2] = fmaf(a.w, b.z, acc[3][2]);
            acc[3][3] = fmaf(a.w, b.w, acc[3][3]);
        }
    }
#pragma unroll
    for (int r = 0; r < 4; ++r) {
#pragma unroll
        for (int c = 0; c < 4; ++c) {
            float v = acc[r][c];
            if (bias) v += bias[n0 + tn + c];
            C[(size_t)(m0 + tm + r) * ldc + coff + n0 + tn + c] = v;
        }
    }
}

// ---------------- MFMA LSTM recurrence ----------------
// 32 blocks = (dir, batch); 1024 threads = 16 waves; wave w owns rows [w*64, w*64+64)
// (4 m-tiles of 16). Weights as 16x16x32 A-frags: 23 in VGPRs, 9 in LDS.
// B = h (f16[256]) broadcast from LDS, wave-uniform addr per k-chunk.
__global__ __launch_bounds__(1024, 4) void lstm_mfma(const float* __restrict__ gx,
                                                     const uint32_t* __restrict__ wpk_layer,
                                                     float* __restrict__ xout) {
    extern __shared__ uint32_t smem[];
    uint32_t* wtail = smem;                    // 16*9*64*4 = 36864 dw (144 KB)
    float*    gbuf  = (float*)(smem + 36864);  // 1024 f32
    uint32_t* hsta  = smem + 37888;            // 128 dw = 256 f16

    const int d = blockIdx.x >> 4;
    const int b = blockIdx.x & 15;
    const int t = threadIdx.x;
    const int w = t >> 6;
    const int l = t & 63;
    const int cgrp = l >> 4;

    // one-time: load 23 reg frags, stage 9 tail frags to LDS
    uint4 wreg[23];
    const uint32_t* wsrc = wpk_layer + (((size_t)d * 64 + w * 4) * 8) * 256;
#pragma unroll
    for (int mtl = 0; mtl < 4; ++mtl)
#pragma unroll
        for (int kc = 0; kc < 8; ++kc) {
            int f = mtl * 8 + kc;
            uint4 v = *(const uint4*)&wsrc[((size_t)mtl * 8 + kc) * 256 + l * 4];
            if (f < 23) wreg[f] = v;
            else *(uint4*)&wtail[((w * 9 + (f - 23)) * 64 + l) * 4] = v;
        }
    if (t < 128) hsta[t] = 0u;
    float creg = 0.f;
    float gxi = 0.f, gxf = 0.f, gxg = 0.f, gxo = 0.f;
    const float* gxb = gx + ((size_t)d * 1600 + b * 100) * 1024;
    if (t < 256) {
        int tt0 = d ? NL - 1 : 0;
        gxi = gxb[(size_t)tt0 * 1024 + t];
        gxf = gxb[(size_t)tt0 * 1024 + 256 + t];
        gxg = gxb[(size_t)tt0 * 1024 + 512 + t];
        gxo = gxb[(size_t)tt0 * 1024 + 768 + t];
    }
    __syncthreads();

    for (int s = 0; s < NL; ++s) {
        const int tt = d ? (NL - 1 - s) : s;
        f32x4 acc0 = {0.f, 0.f, 0.f, 0.f};
        f32x4 acc1 = {0.f, 0.f, 0.f, 0.f};
        f32x4 acc2 = {0.f, 0.f, 0.f, 0.f};
        f32x4 acc3 = {0.f, 0.f, 0.f, 0.f};
#pragma unroll
        for (int kc = 0; kc < 8; ++kc) {
            uint4 braw = *(const uint4*)&hsta[kc * 16 + cgrp * 4];
            f16x8 B = __builtin_bit_cast(f16x8, braw);
            acc0 = __builtin_amdgcn_mfma_f32_16x16x32_f16(
                __builtin_bit_cast(f16x8, wreg[kc]), B, acc0, 0, 0, 0);
            acc1 = __builtin_amdgcn_mfma_f32_16x16x32_f16(
                __builtin_bit_cast(f16x8, wreg[8 + kc]), B, acc1, 0, 0, 0);
            uint4 a2raw = (kc < 7) ? wreg[16 + kc]
                                   : *(const uint4*)&wtail[((w * 9 + 0) * 64 + l) * 4];
            acc2 = __builtin_amdgcn_mfma_f32_16x16x32_f16(
                __builtin_bit_cast(f16x8, a2raw), B, acc2, 0, 0, 0);
            uint4 a3raw = *(const uint4*)&wtail[((w * 9 + kc + 1) * 64 + l) * 4];
            acc3 = __builtin_amdgcn_mfma_f32_16x16x32_f16(
                __builtin_bit_cast(f16x8, a3raw), B, acc3, 0, 0, 0);
        }
        if ((l & 15) == 0) {
            *(f32x4*)&gbuf[w * 64 +  0 + cgrp * 4] = acc0;
            *(f32x4*)&gbuf[w * 64 + 16 + cgrp * 4] = acc1;
            *(f32x4*)&gbuf[w * 64 + 32 + cgrp * 4] = acc2;
            *(f32x4*)&gbuf[w * 64 + 48 + cgrp * 4] = acc3;
        }
        __syncthreads();
        if (t < 256) {
            float gi = gbuf[t] + gxi;
            float gf = gbuf[256 + t] + gxf;
            float gg = gbuf[512 + t] + gxg;
            float go = gbuf[768 + t] + gxo;
            float cn = fmaf(sigm(gf), creg, sigm(gi) * tanh_(gg));
            creg = cn;
            float hn = sigm(go) * tanh_(cn);
            ((_Float16*)hsta)[t] = (_Float16)hn;
            xout[((size_t)b * NL + tt) * 512 + d * 256 + t] = hn;
            if (s + 1 < NL) {
                int tn = d ? (NL - 2 - s) : (s + 1);
                gxi = gxb[(size_t)tn * 1024 + t];
                gxf = gxb[(size_t)tn * 1024 + 256 + t];
                gxg = gxb[(size_t)tn * 1024 + 512 + t];
                gxo = gxb[(size_t)tn * 1024 + 768 + t];
            }
        }
        __syncthreads();
    }
}

// ---------------- MFMA scorer ----------------
// block: batch b, 16 i x 8 j = 128 pairs (8 m-tiles), 128 channels (8 n-tiles), K=512.
// A = relu(hf_i + hr_j + b1) built in-register, split-f16 (hi+lo).
// B = W2 split-f16 frags staged per 32-k chunk. 3-term MFMA (hi*hi + hi*lo + lo*hi).
__global__ __launch_bounds__(256) void scorer_mfma(const float* __restrict__ hfr,
                                                   const uint32_t* __restrict__ w2pk,
                                                   const float* __restrict__ b1,
                                                   const float* __restrict__ b2,
                                                   const float* __restrict__ W3,
                                                   const float* __restrict__ b3,
                                                   const int* __restrict__ sen_lens,
                                                   float* __restrict__ out) {
    extern __shared__ uint32_t smem[];
    float*    hfs = (float*)smem;               // [16][520]
    float*    hrs = hfs + 16 * 520;             // [8][520]
    float*    b1s = hrs + 8 * 520;              // [512]
    uint32_t* w2s = (uint32_t*)(b1s + 512);     // [1024][4] dw = 16 KB

    const int t = threadIdx.x;
    const int wv = t >> 6, l = t & 63;
    const int cgrp = l >> 4;
    const int b = blockIdx.z;
    const int i0 = blockIdx.x * 16;
    const int j0 = blockIdx.y * 8;

    // stage hf rows (i0..i0+15), hr rows (j0..j0+7 -> source j-1), b1
#pragma unroll
    for (int rep = 0; rep < 8; ++rep) {
        int slot = rep * 256 + t;
        int row = slot >> 7, c4 = slot & 127;
        int i = i0 + row;
        float4 v = make_float4(0.f, 0.f, 0.f, 0.f);
        if (i < 100) v = *(const float4*)&hfr[((size_t)b * 100 + i) * 1024 + c4 * 4];
        *(float4*)&hfs[row * 520 + c4 * 4] = v;
    }
#pragma unroll
    for (int rep = 0; rep < 4; ++rep) {
        int slot = rep * 256 + t;
        int row = slot >> 7, c4 = slot & 127;
        int j = j0 + row;
        float4 v = make_float4(0.f, 0.f, 0.f, 0.f);
        if (j >= 1 && j <= 100)
            v = *(const float4*)&hfr[((size_t)b * 100 + (j - 1)) * 1024 + 512 + c4 * 4];
        *(float4*)&hrs[row * 520 + c4 * 4] = v;
    }
    if (t < 128) *(float4*)&b1s[t * 4] = *(const float4*)&b1[t * 4];

    float b2r[8], w3r[8];
#pragma unroll
    for (int nt = 0; nt < 8; ++nt) {
        b2r[nt] = b2[nt * 16 + (l & 15)];
        w3r[nt] = W3[nt * 16 + (l & 15)];
    }
    f32x4 accA[8], accB[8];
#pragma unroll
    for (int nt = 0; nt < 8; ++nt) {
        accA[nt] = (f32x4){0.f, 0.f, 0.f, 0.f};
        accB[nt] = (f32x4){0.f, 0.f, 0.f, 0.f};
    }
    const int p0 = (wv * 2) * 16 + (l & 15);
    const int p1 = (wv * 2 + 1) * 16 + (l & 15);
    const int ilA = p0 >> 3, jlA = p0 & 7;
    const int ilB = p1 >> 3, jlB = p1 & 7;
    __syncthreads();

    for (int kc = 0; kc < 16; ++kc) {
        // stage W2 chunk (16 KB, lane-linear frag layout)
#pragma unroll
        for (int rep = 0; rep < 4; ++rep) {
            int slot = rep * 256 + t;
            *(uint4*)&w2s[slot * 4] = *(const uint4*)&w2pk[((size_t)kc * 1024 + slot) * 4];
        }
        __syncthreads();
        // build A-frags for both m-tiles
        const int k0 = kc * 32 + cgrp * 8;
        f16x8 ahi0, alo0, ahi1, alo1;
        {
            const float* hf = &hfs[ilA * 520 + k0];
            const float* hr = &hrs[jlA * 520 + k0];
            const float* bb = &b1s[k0];
#pragma unroll
            for (int j = 0; j < 8; ++j) {
                float v = fmaxf(hf[j] + hr[j] + bb[j], 0.f);
                _Float16 hi = (_Float16)v;
                ahi0[j] = hi;
                alo0[j] = (_Float16)(v - (float)hi);
            }
        }
        {
            const float* hf = &hfs[ilB * 520 + k0];
            const float* hr = &hrs[jlB * 520 + k0];
            const float* bb = &b1s[k0];
#pragma unroll
            for (int j = 0; j < 8; ++j) {
                float v = fmaxf(hf[j] + hr[j] + bb[j], 0.f);
                _Float16 hi = (_Float16)v;
                ahi1[j] = hi;
                alo1[j] = (_Float16)(v - (float)hi);
            }
        }
#pragma unroll
        for (int nt = 0; nt < 8; ++nt) {
            f16x8 bhi = __builtin_bit_cast(f16x8, *(const uint4*)&w2s[((0 * 8 + nt) * 64 + l) * 4]);
            f16x8 blo = __builtin_bit_cast(f16x8, *(const uint4*)&w2s[((1 * 8 + nt) * 64 + l) * 4]);
            accA[nt] = __builtin_amdgcn_mfma_f32_16x16x32_f16(ahi0, bhi, accA[nt], 0, 0, 0);
            accA[nt] = __builtin_amdgcn_mfma_f32_16x16x32_f16(ahi0, blo, accA[nt], 0, 0, 0);
            accA[nt] = __builtin_amdgcn_mfma_f32_16x16x32_f16(alo0, bhi, accA[nt], 0, 0, 0);
            accB[nt] = __builtin_amdgcn_mfma_f32_16x16x32_f16(ahi1, bhi, accB[nt], 0, 0, 0);
            accB[nt] = __builtin_amdgcn_mfma_f32_16x16x32_f16(ahi1, blo, accB[nt], 0, 0, 0);
            accB[nt] = __builtin_amdgcn_mfma_f32_16x16x32_f16(alo1, bhi, accB[nt], 0, 0, 0);
        }
        __syncthreads();
    }
    // epilogue: h2 = relu(acc + b2); sc = h2 . W3; reduce over 16 lanes (channels)
    float sp0[4] = {0.f, 0.f, 0.f, 0.f};
    float sp1[4] = {0.f, 0.f, 0.f, 0.f};
#pragma unroll
    for (int nt = 0; nt < 8; ++nt)
#pragma unroll
        for (int r = 0; r < 4; ++r) {
            sp0[r] += fmaxf(accA[nt][r] + b2r[nt], 0.f) * w3r[nt];
            sp1[r] += fmaxf(accB[nt][r] + b2r[nt], 0.f) * w3r[nt];
        }
#pragma unroll
    for (int r = 0; r < 4; ++r) {
#pragma unroll
        for (int off = 1; off < 16; off <<= 1) {
            sp0[r] += __shfl_xor(sp0[r], off);
            sp1[r] += __shfl_xor(sp1[r], off);
        }
    }
    if ((l & 15) == 0) {
        float bias3 = b3[0];
        int sl = sen_lens[b];
#pragma unroll
        for (int mtl = 0; mtl < 2; ++mtl)
#pragma unroll
            for (int r = 0; r < 4; ++r) {
                int p = (wv * 2 + mtl) * 16 + cgrp * 4 + r;
                int i = i0 + (p >> 3), j = j0 + (p & 7);
                if (i < 100 && j < 101) {
                    float v = (mtl == 0 ? sp0[r] : sp1[r]) + bias3;
                    if (!((i < sl) && (j <= sl)) || (i == 0 && j == 0)) v = 0.f;
                    out[((size_t)b * 101 + i) * 101 + j] = v;
                }
            }
    }
}

// ---------------- launcher ----------------
extern "C" void kernel_launch(void* const* d_in, const int* in_sizes, int n_in,
                              void* d_out, int out_size, void* d_ws, size_t ws_size,
                              hipStream_t stream) {
    const float* we       = (const float*)d_in[0];
    const int*   pos_idx  = (const int*)d_in[1];
    const int*   sen_lens = (const int*)d_in[2];
    const float* pos_emb  = (const float*)d_in[3];
    const float* w_ih0    = (const float*)d_in[4];
    const float* w_hh0    = (const float*)d_in[5];
    const float* b_ih0    = (const float*)d_in[6];
    const float* b_hh0    = (const float*)d_in[7];
    const float* w_ih     = (const float*)d_in[8];
    const float* w_hh     = (const float*)d_in[9];
    const float* b_ih     = (const float*)d_in[10];
    const float* b_hh     = (const float*)d_in[11];
    const float* W1       = (const float*)d_in[12];
    const float* b1       = (const float*)d_in[13];
    const float* W2       = (const float*)d_in[14];
    const float* b2       = (const float*)d_in[15];
    const float* W3       = (const float*)d_in[16];
    const float* b3       = (const float*)d_in[17];
    float* out = (float*)d_out;

    float* ws    = (float*)d_ws;
    float* x0p   = ws;                        // 256000
    float* gx    = x0p + 256000;              // 3276800
    float* xA    = gx + 3276800;              // 819200
    float* xB    = xA + 819200;               // 819200
    float* hfr   = xB + 819200;               // 1638400
    float* wi0p  = hfr + 1638400;             // 327680
    float* biasp = wi0p + 327680;             // 8192
    uint32_t* wpk  = (uint32_t*)(biasp + 8192);   // 1048576 dw (4 layers)
    uint32_t* w2pk = wpk + 1048576;               // 65536 dw

    pack_whh_mfma<<<1024, 256, 0, stream>>>(w_hh0, w_hh, wpk);
    pack_w2_mfma<<<64, 256, 0, stream>>>(W2, w2pk);
    pack_wi0<<<1280, 256, 0, stream>>>(w_ih0, wi0p);
    pack_bias<<<32, 256, 0, stream>>>(b_ih0, b_hh0, b_ih, b_hh, biasp);
    concat_x0<<<1000, 256, 0, stream>>>(we, pos_idx, pos_emb, x0p);

    const int LSTM_SMEM = 38016 * 4;     // 152064 B
    const int SCOR_SMEM = 68352;         // hfs/hrs/b1s + w2s

    // layer 0: K=160 (padded)
    for (int d = 0; d < 2; ++d)
        gemm_xwT<<<dim3(25, 16), 256, 0, stream>>>(
            x0p, wi0p + (size_t)d * 1024 * 160, biasp + d * 1024,
            gx + (size_t)d * 1600 * 1024, 160, 160, 160, 1024, 0);
    lstm_mfma<<<32, 1024, LSTM_SMEM, stream>>>(gx, wpk, xA);

    const float* xin = xA;
    float* xo = xB;
    for (int l = 1; l < 4; ++l) {
        for (int d = 0; d < 2; ++d)
            gemm_xwT<<<dim3(25, 16), 256, 0, stream>>>(
                xin, w_ih + (((size_t)(l - 1) * 2 + d) * 1024) * 512,
                biasp + (l * 2 + d) * 1024,
                gx + (size_t)d * 1600 * 1024, 512, 512, 512, 1024, 0);
        lstm_mfma<<<32, 1024, LSTM_SMEM, stream>>>(gx, wpk + (size_t)l * 262144, xo);
        float* tmp = (float*)xin; xin = xo; xo = tmp;
    }
    const float* lstm_out = xin;

    gemm_xwT<<<dim3(25, 8), 256, 0, stream>>>(lstm_out, W1, nullptr, hfr,
                                              512, 512, 1024, 1024, 0);
    gemm_xwT<<<dim3(25, 8), 256, 0, stream>>>(lstm_out, W1 + 512, nullptr, hfr,
                                              512, 512, 1024, 1024, 512);

    zero_out<<<(NOUT + 255) / 256, 256, 0, stream>>>(out);
    scorer_mfma<<<dim3(7, 13, 16), 256, SCOR_SMEM, stream>>>(hfr, w2pk, b1, b2, W3, b3,
                                                             sen_lens, out);
}